// Round 11
// baseline (1086.269 us; speedup 1.0000x reference)
//
#include <hip/hip_runtime.h>
#include <stdint.h>

#define DEVI __device__ __forceinline__

typedef unsigned short u16;
typedef short s8v __attribute__((ext_vector_type(8)));
typedef float f4v __attribute__((ext_vector_type(4)));
typedef u16 u16x4 __attribute__((ext_vector_type(4)));

DEVI u16 f2bf(float f) {
  unsigned u = __float_as_uint(f);
  u += 0x7fffu + ((u >> 16) & 1u);
  return (u16)(u >> 16);
}
DEVI float bf2f(u16 h) { return __uint_as_float(((unsigned)h) << 16); }

DEVI void gload16(const void* g, void* l) {
  __builtin_amdgcn_global_load_lds(
      (const __attribute__((address_space(1))) void*)(uintptr_t)g,
      (__attribute__((address_space(3))) void*)(uintptr_t)l, 16, 0, 0);
}

// ---------------- transpose + f32->bf16 convert: W[R][C] -> Wt[C][R] ----------
__global__ __launch_bounds__(256) void transpose_w(const float* __restrict__ W,
                                                   u16* __restrict__ Wt, int R, int C) {
  __shared__ float tile[32][33];
  const int tx = threadIdx.x & 31, ty = threadIdx.x >> 5;
  const int r0 = blockIdx.y * 32, c0 = blockIdx.x * 32;
#pragma unroll
  for (int i = 0; i < 4; ++i)
    tile[ty + 8 * i][tx] = W[(size_t)(r0 + ty + 8 * i) * C + c0 + tx];
  __syncthreads();
#pragma unroll
  for (int i = 0; i < 4; ++i)
    Wt[(size_t)(c0 + ty + 8 * i) * R + r0 + tx] = f2bf(tile[tx][ty + 8 * i]);
}

// ------- row LayerNorm (D=1024), f32 in -> bf16 out; optionally zero zbuf[row]
__global__ __launch_bounds__(256) void ln_rows(const float* __restrict__ x,
                                               const float* __restrict__ g,
                                               const float* __restrict__ bsh,
                                               u16* __restrict__ y,
                                               float* __restrict__ zbuf) {
  const size_t row = blockIdx.x;
  const int t = threadIdx.x;
  if (zbuf && t == 0) zbuf[row] = 0.f;
  float4 v = ((const float4*)(x + row * 1024))[t];
  float s = v.x + v.y + v.z + v.w;
  float q = v.x * v.x + v.y * v.y + v.z * v.z + v.w * v.w;
#pragma unroll
  for (int m = 1; m < 64; m <<= 1) { s += __shfl_xor(s, m); q += __shfl_xor(q, m); }
  __shared__ float sh[8];
  if ((t & 63) == 0) { sh[t >> 6] = s; sh[4 + (t >> 6)] = q; }
  __syncthreads();
  s = sh[0] + sh[1] + sh[2] + sh[3];
  q = sh[4] + sh[5] + sh[6] + sh[7];
  const float mu = s * (1.f / 1024.f);
  const float var = q * (1.f / 1024.f) - mu * mu;
  const float rs = rsqrtf(var + 1e-5f);
  const int c = t * 4;
  const float in[4] = {v.x, v.y, v.z, v.w};
  u16x4 o;
#pragma unroll
  for (int i = 0; i < 4; ++i) o[i] = f2bf((in[i] - mu) * rs * g[c + i] + bsh[c + i]);
  *(u16x4*)(y + row * 1024 + c) = o;
}

// ====== 256x256 MFMA GEMM, BK=64, 2-slot dbuf, TOP-STAGED counted vmcnt(8) ===
// Fixes R9's end-of-tile vmcnt(0) drain (R10's depth-3 ring blew the 160KB
// LDS limit: 4x64KB).  Per iter T (slot SL=T&1, SN=(T+1)&1):
//   barrier1   -- all waves done reading slot SN (tile T-1; their ds_reads are
//                 lgkm-waited before the iter T-1 MFMAs that consume them)
//   stage tile T+1 -> slot SN   (8 gloads; clamped tail keeps counts uniform:
//                 iter NT-1 re-stages tile NT-1 into the dead slot, never read)
//   vmcnt(8)   -- issued = 8+8(T+1); completed >= 8(T+1) => tile T resident
//                 (own loads; issued a FULL TILE earlier => ~zero wait)
//   barrier2   -- residency collective across waves
//   4 phases { ds_reads(slot SL) quadrant + setprio1 + 16 MFMA + setprio0 }
//     no fences, no gloads inside: compiler inserts counted lgkm per dep.
// Swizzle (128-B rows): LDS[r][chunk c] holds global k-chunk c^(r&7); write
// linear dest + pre-swizzled global col; read kx0/kx1.  (verified 0-conflict)
// EPI 0: fused KV epilogue (col0<1024 -> K-path w/ rowssq+gain, else V-path)
// EPI 1: CK bf16 = gelu_exact(acc + biasK[col]), ldc = N.
template <int EPI, int KK>
__global__ __launch_bounds__(512, 2) void gemm256(
    const u16* __restrict__ A, const u16* __restrict__ Bt,
    const float* __restrict__ biasK, const float* __restrict__ biasV,
    const float* __restrict__ gcol, u16* __restrict__ CK, u16* __restrict__ CV,
    float* __restrict__ rowssq, int M, int N, int RB, int CB) {
  __shared__ u16 lds[2][32768];  // slot: A [256][64] (32KB) then B [256][64]
  const int t = threadIdx.x;
  const int lane = t & 63;
  const int wave = t >> 6;
  const int wm = wave >> 2, wn = wave & 3;
  const int fr = lane & 15, kq = lane >> 4;

  const int bid = blockIdx.x;
  const int cpx = gridDim.x >> 3;
  const int swz = (bid & 7) * cpx + (bid >> 3);
  const int rb = swz / CB, cb = swz % CB;  // cb-fastest
  const size_t row0 = (size_t)rb * 256, col0 = (size_t)cb * 256;

  f4v acc[8][4];
#pragma unroll
  for (int i = 0; i < 8; ++i)
#pragma unroll
    for (int n = 0; n < 4; ++n) acc[i][n] = (f4v){0.f, 0.f, 0.f, 0.f};

  // stage addressing: thread t -> row (t>>3)+j*64, LDS chunk t&7 (linear dest),
  // global chunk pre-swizzled
  const int srow = t >> 3;
  const int scol = (((t & 7) ^ (srow & 7)) << 3);
  const u16* Ag = A + (row0 + srow) * (size_t)KK + scol;
  const u16* Bg = Bt + (col0 + srow) * (size_t)KK + scol;
  char* dA[2];
  char* dB[2];
  const char* lb = (const char*)&lds[0][0];
#pragma unroll
  for (int s = 0; s < 2; ++s) {
    dA[s] = (char*)lb + s * 65536 + t * 16;
    dB[s] = (char*)lb + s * 65536 + 32768 + t * 16;
  }

  // read bases
  const int f7 = fr & 7;
  const int kx0 = ((kq ^ f7) << 4);
  const int kx1 = kx0 ^ 64;
  const char* bA[2][2];
  const char* bB[2][2];
#pragma unroll
  for (int s = 0; s < 2; ++s) {
    bA[s][0] = lb + s * 65536 + (wm * 128 + fr) * 128 + kx0;
    bA[s][1] = lb + s * 65536 + (wm * 128 + fr) * 128 + kx1;
    bB[s][0] = lb + s * 65536 + 32768 + (wn * 64 + fr) * 128 + kx0;
    bB[s][1] = lb + s * 65536 + 32768 + (wn * 64 + fr) * 128 + kx1;
  }

  const int NT = KK >> 6;  // BK=64; 16 for KK=1024 (even)

  // prologue: stage tile 0 into slot 0 (8 loads); loop's vmcnt(8) covers it
#pragma unroll
  for (int j = 0; j < 4; ++j) {
    gload16(Ag + (size_t)j * 64 * KK, dA[0] + j * 8192);
    gload16(Bg + (size_t)j * 64 * KK, dB[0] + j * 8192);
  }

#define KV_ITER(T_, SL, SN)                                                      \
  {                                                                              \
    __builtin_amdgcn_s_barrier(); /* barrier1: slot SN reads (tile T-1) done */  \
    const int Ts = (T_ + 1 < NT) ? T_ + 1 : NT - 1;                              \
    const u16* Agt = Ag + (size_t)Ts * 64;                                       \
    const u16* Bgt = Bg + (size_t)Ts * 64;                                       \
    gload16(Agt, dA[SN]);                                                        \
    gload16(Agt + (size_t)64 * KK, dA[SN] + 8192);                               \
    gload16(Agt + (size_t)128 * KK, dA[SN] + 16384);                             \
    gload16(Agt + (size_t)192 * KK, dA[SN] + 24576);                             \
    gload16(Bgt, dB[SN]);                                                        \
    gload16(Bgt + (size_t)64 * KK, dB[SN] + 8192);                               \
    gload16(Bgt + (size_t)128 * KK, dB[SN] + 16384);                             \
    gload16(Bgt + (size_t)192 * KK, dB[SN] + 24576);                             \
    asm volatile("s_waitcnt vmcnt(8)" ::: "memory"); /* tile T landed (own) */   \
    __builtin_amdgcn_s_barrier();                    /* collective residency */  \
    __builtin_amdgcn_sched_barrier(0);                                           \
    s8v a[8], b0[4], b1[4];                                                      \
    /* ---- ph0: quadrant (mh0,nh0) ---- */                                      \
    _Pragma("unroll") for (int m = 0; m < 4; ++m) {                              \
      a[2 * m] = *(const s8v*)(bA[SL][0] + m * 2048);                            \
      a[2 * m + 1] = *(const s8v*)(bA[SL][1] + m * 2048);                        \
    }                                                                            \
    _Pragma("unroll") for (int n = 0; n < 2; ++n) {                              \
      b0[2 * n] = *(const s8v*)(bB[SL][0] + n * 2048);                           \
      b0[2 * n + 1] = *(const s8v*)(bB[SL][1] + n * 2048);                       \
    }                                                                            \
    __builtin_amdgcn_s_setprio(1);                                               \
    _Pragma("unroll") for (int m = 0; m < 4; ++m)                                \
        _Pragma("unroll") for (int n = 0; n < 2; ++n) {                          \
      acc[m][n] = __builtin_amdgcn_mfma_f32_16x16x32_bf16(a[2 * m], b0[2 * n],   \
                                                          acc[m][n], 0, 0, 0);   \
      acc[m][n] = __builtin_amdgcn_mfma_f32_16x16x32_bf16(                       \
          a[2 * m + 1], b0[2 * n + 1], acc[m][n], 0, 0, 0);                      \
    }                                                                            \
    __builtin_amdgcn_s_setprio(0);                                               \
    /* ---- ph1: quadrant (mh0,nh1) ---- */                                      \
    _Pragma("unroll") for (int n = 0; n < 2; ++n) {                              \
      b1[2 * n] = *(const s8v*)(bB[SL][0] + 4096 + n * 2048);                    \
      b1[2 * n + 1] = *(const s8v*)(bB[SL][1] + 4096 + n * 2048);                \
    }                                                                            \
    __builtin_amdgcn_s_setprio(1);                                               \
    _Pragma("unroll") for (int m = 0; m < 4; ++m)                                \
        _Pragma("unroll") for (int n = 0; n < 2; ++n) {                          \
      acc[m][2 + n] = __builtin_amdgcn_mfma_f32_16x16x32_bf16(                   \
          a[2 * m], b1[2 * n], acc[m][2 + n], 0, 0, 0);                          \
      acc[m][2 + n] = __builtin_amdgcn_mfma_f32_16x16x32_bf16(                   \
          a[2 * m + 1], b1[2 * n + 1], acc[m][2 + n], 0, 0, 0);                  \
    }                                                                            \
    __builtin_amdgcn_s_setprio(0);                                               \
    /* ---- ph2: quadrant (mh1,nh1), overwrite a ---- */                         \
    _Pragma("unroll") for (int m = 0; m < 4; ++m) {                              \
      a[2 * m] = *(const s8v*)(bA[SL][0] + 8192 + m * 2048);                     \
      a[2 * m + 1] = *(const s8v*)(bA[SL][1] + 8192 + m * 2048);                 \
    }                                                                            \
    __builtin_amdgcn_s_setprio(1);                                               \
    _Pragma("unroll") for (int m = 0; m < 4; ++m)                                \
        _Pragma("unroll") for (int n = 0; n < 2; ++n) {                          \
      acc[4 + m][2 + n] = __builtin_amdgcn_mfma_f32_16x16x32_bf16(               \
          a[2 * m], b1[2 * n], acc[4 + m][2 + n], 0, 0, 0);                      \
      acc[4 + m][2 + n] = __builtin_amdgcn_mfma_f32_16x16x32_bf16(               \
          a[2 * m + 1], b1[2 * n + 1], acc[4 + m][2 + n], 0, 0, 0);              \
    }                                                                            \
    __builtin_amdgcn_s_setprio(0);                                               \
    /* ---- ph3: quadrant (mh1,nh0), b0 still live ---- */                       \
    __builtin_amdgcn_s_setprio(1);                                               \
    _Pragma("unroll") for (int m = 0; m < 4; ++m)                                \
        _Pragma("unroll") for (int n = 0; n < 2; ++n) {                          \
      acc[4 + m][n] = __builtin_amdgcn_mfma_f32_16x16x32_bf16(                   \
          a[2 * m], b0[2 * n], acc[4 + m][n], 0, 0, 0);                          \
      acc[4 + m][n] = __builtin_amdgcn_mfma_f32_16x16x32_bf16(                   \
          a[2 * m + 1], b0[2 * n + 1], acc[4 + m][n], 0, 0, 0);                  \
    }                                                                            \
    __builtin_amdgcn_s_setprio(0);                                               \
  }

  for (int T = 0; T < NT; T += 2) {
    KV_ITER(T, 0, 1);
    KV_ITER((T + 1), 1, 0);
  }
#undef KV_ITER

  // ---- epilogue ----
  const int kq4 = kq * 4;
  if (EPI == 0) {
    const bool isK = (col0 < 1024);
    if (isK) {
#pragma unroll
      for (int ai = 0; ai < 8; ++ai) {
        int cols[4];
        float bb[4], gg[4];
#pragma unroll
        for (int n = 0; n < 4; ++n) {
          cols[n] = (int)col0 + wn * 64 + n * 16 + fr;
          bb[n] = biasK[cols[n]];
          gg[n] = gcol[cols[n]];
        }
#pragma unroll
        for (int r = 0; r < 4; ++r) {
          const size_t grow = row0 + wm * 128 + ai * 16 + kq4 + r;
          float v[4];
#pragma unroll
          for (int n = 0; n < 4; ++n) v[n] = acc[ai][n][r] + bb[n];
          float s = v[0] * v[0] + v[1] * v[1] + v[2] * v[2] + v[3] * v[3];
          s += __shfl_xor(s, 1);
          s += __shfl_xor(s, 2);
          s += __shfl_xor(s, 4);
          s += __shfl_xor(s, 8);
          if (fr == 0) atomicAdd(&rowssq[grow], s);
#pragma unroll
          for (int n = 0; n < 4; ++n)
            CK[grow * 1024 + cols[n]] = f2bf(v[n] * gg[n]);
        }
      }
    } else {
#pragma unroll
      for (int ai = 0; ai < 8; ++ai) {
        int cols[4];
        float bb[4];
#pragma unroll
        for (int n = 0; n < 4; ++n) {
          cols[n] = (int)col0 - 1024 + wn * 64 + n * 16 + fr;
          bb[n] = biasV[cols[n]];
        }
#pragma unroll
        for (int r = 0; r < 4; ++r) {
          const size_t grow = row0 + wm * 128 + ai * 16 + kq4 + r;
#pragma unroll
          for (int n = 0; n < 4; ++n)
            CV[grow * 1024 + cols[n]] = f2bf(acc[ai][n][r] + bb[n]);
        }
      }
    }
  } else {
#pragma unroll
    for (int ai = 0; ai < 8; ++ai) {
      int cols[4];
      float bb[4];
#pragma unroll
      for (int n = 0; n < 4; ++n) {
        cols[n] = (int)col0 + wn * 64 + n * 16 + fr;
        bb[n] = biasK[cols[n]];
      }
#pragma unroll
      for (int r = 0; r < 4; ++r) {
        const size_t grow = row0 + wm * 128 + ai * 16 + kq4 + r;
#pragma unroll
        for (int n = 0; n < 4; ++n) {
          const float x = acc[ai][n][r] + bb[n];
          CK[grow * (size_t)N + cols[n]] = f2bf(0.5f * x * (1.f + erff(x * 0.70710678118654752f)));
        }
      }
    }
  }
}

// ---------------- 128x128 MFMA GEMM (m97 structure), epilogues ---------------
// EPI 3: store f32 (acc+bias+extra[row,col])
// EPI 5: v=acc+bias; atomic rowssq += v^2; store bf16 v   (q-path)
// EPI 6: split-K partial: store f32 raw acc to Cv + z*M*N; K-range by blockIdx.z
template <int EPI>
__global__ __launch_bounds__(256) void gemm_bt(
    const u16* __restrict__ A, const u16* __restrict__ Bt,
    const float* __restrict__ bias, const float* __restrict__ gcol,
    void* __restrict__ Cv, const float* __restrict__ extra,
    float* __restrict__ rowssq, int M, int N, int K) {
  __shared__ u16 As[128 * 32];
  __shared__ u16 Bs[128 * 32];
  const int t = threadIdx.x;
  const int lane = t & 63;
  const int wave = t >> 6;
  const int wr = wave >> 1, wc = wave & 1;
  const size_t row0 = (size_t)blockIdx.y * 128;
  const size_t col0 = (size_t)blockIdx.x * 128;
  int Ksub = K, koff = 0;
  if (EPI == 6) { Ksub = K / gridDim.z; koff = blockIdx.z * Ksub; }

  f4v acc[4][4];
#pragma unroll
  for (int m = 0; m < 4; ++m)
#pragma unroll
    for (int n = 0; n < 4; ++n) acc[m][n] = (f4v){0.f, 0.f, 0.f, 0.f};

  const int sr = t >> 2;
  const int scw = (((t & 3) ^ ((t >> 3) & 3)) << 3);  // pre-swizzled global col
  const u16* Ag = A + (row0 + sr) * (size_t)K + koff + scw;
  const u16* Bg = Bt + (col0 + sr) * (size_t)K + koff + scw;
  u16* Al = &As[t * 8];  // linear dest
  u16* Bl = &Bs[t * 8];
  const int fr = lane & 15;
  const int kx = (((lane >> 4) ^ ((fr >> 1) & 3)) << 3);

  for (int k0 = 0; k0 < Ksub; k0 += 32) {
    gload16(Ag + k0, Al);
    gload16(Ag + k0 + (size_t)64 * K, Al + 64 * 32);
    gload16(Bg + k0, Bl);
    gload16(Bg + k0 + (size_t)64 * K, Bl + 64 * 32);
    __syncthreads();
    s8v a[4], b[4];
#pragma unroll
    for (int m = 0; m < 4; ++m)
      a[m] = *(const s8v*)&As[(wr * 64 + m * 16 + fr) * 32 + kx];
#pragma unroll
    for (int n = 0; n < 4; ++n)
      b[n] = *(const s8v*)&Bs[(wc * 64 + n * 16 + fr) * 32 + kx];
#pragma unroll
    for (int m = 0; m < 4; ++m)
#pragma unroll
      for (int n = 0; n < 4; ++n)
        acc[m][n] = __builtin_amdgcn_mfma_f32_16x16x32_bf16(a[m], b[n], acc[m][n], 0, 0, 0);
    __syncthreads();
  }

  float* Cp = (float*)Cv;
  if (EPI == 6) Cp += (size_t)blockIdx.z * M * (size_t)N;
  const int rg = (lane >> 4) * 4;
#pragma unroll
  for (int m = 0; m < 4; ++m) {
    int cols[4];
    float bvals[4];
#pragma unroll
    for (int n = 0; n < 4; ++n) {
      cols[n] = (int)col0 + wc * 64 + n * 16 + fr;
      bvals[n] = (EPI == 6) ? 0.f : bias[cols[n]];
    }
#pragma unroll
    for (int r = 0; r < 4; ++r) {
      const size_t grow = row0 + wr * 64 + m * 16 + rg + r;
      float v[4];
#pragma unroll
      for (int n = 0; n < 4; ++n) v[n] = acc[m][n][r] + bvals[n];
      if (EPI == 5) {
        float s = v[0] * v[0] + v[1] * v[1] + v[2] * v[2] + v[3] * v[3];
        s += __shfl_xor(s, 1);
        s += __shfl_xor(s, 2);
        s += __shfl_xor(s, 4);
        s += __shfl_xor(s, 8);
        if (fr == 0) atomicAdd(&rowssq[grow], s);
      }
#pragma unroll
      for (int n = 0; n < 4; ++n) {
        const size_t idx = grow * (size_t)N + cols[n];
        if (EPI == 3) {
          Cp[idx] = v[n] + extra[idx];
        } else if (EPI == 5) {
          ((u16*)Cv)[idx] = f2bf(v[n]);
        } else if (EPI == 6) {
          Cp[idx] = v[n];
        }
      }
    }
  }
}

// ---------------- attention with the faithful raw-reshape semantics ----------
// head h, key j in [0,32): kv position = 2h + j/16, d-slice = (j%16)*64 .. +64
// q applied here: q_eff[d] = qpre[d]*gq[d]*rsq_q*0.125 (rms of q folded)
__global__ __launch_bounds__(256) void attn_k(const u16* __restrict__ qf,
                                              const u16* __restrict__ kmat,
                                              const float* __restrict__ kssq,
                                              const u16* __restrict__ vmat,
                                              const float* __restrict__ gq,
                                              const float* __restrict__ qssq,
                                              u16* __restrict__ ao) {
  const int lb = blockIdx.x;
  const int t = threadIdx.x;
  const int wave = t >> 6, lane = t & 63;
  const int j = lane & 31, half = lane >> 5;
  const float rq = rsqrtf(qssq[lb] * (1.f / 1024.f) + 1e-6f) * 0.125f;
  __shared__ float po[64][17];
#pragma unroll
  for (int hi = 0; hi < 4; ++hi) {
    const int h = wave * 4 + hi;
    const int krow = lb * 32 + 2 * h + (j >> 4);
    const u16* kp = kmat + (size_t)krow * 1024 + (j & 15) * 64 + half * 32;
    const u16* qp = qf + (size_t)lb * 1024 + h * 64 + half * 32;
    const float* gqp = gq + h * 64 + half * 32;
    float s = 0.f;
#pragma unroll
    for (int cc = 0; cc < 4; ++cc) {
      s8v qv = *(const s8v*)(qp + cc * 8);
      s8v kv = *(const s8v*)(kp + cc * 8);
#pragma unroll
      for (int e = 0; e < 8; ++e)
        s += bf2f((u16)qv[e]) * gqp[cc * 8 + e] * bf2f((u16)kv[e]);
    }
    s += __shfl_xor(s, 32);
    s *= rsqrtf(kssq[krow] * (1.f / 1024.f) + 1e-6f) * rq;
    float mx = s;
#pragma unroll
    for (int m = 16; m >= 1; m >>= 1) mx = fmaxf(mx, __shfl_xor(mx, m));
    const float pe = __expf(s - mx);
    float sum = pe;
#pragma unroll
    for (int m = 16; m >= 1; m >>= 1) sum += __shfl_xor(sum, m);
    const float pr = pe / sum;
    float o = 0.f;
#pragma unroll
    for (int jj = 0; jj < 32; ++jj) {
      const int vrow = lb * 32 + 2 * h + (jj >> 4);
      const float vv = bf2f(vmat[(size_t)vrow * 1024 + (jj & 15) * 64 + lane]);
      o += __shfl(pr, jj) * vv;
    }
    po[lane][h] = o;  // hd = lane
  }
  __syncthreads();
  const int c = t * 4;
  u16x4 o4;
#pragma unroll
  for (int i = 0; i < 4; ++i) o4[i] = f2bf(po[(c + i) >> 4][(c + i) & 15]);
  *(u16x4*)(ao + (size_t)lb * 1024 + c) = o4;
}

// ------------- W2 split-K combine: out = p0 + p1 + b2[col] + resid -----------
__global__ __launch_bounds__(256) void combine_k(const float* __restrict__ p0,
                                                 const float* __restrict__ p1,
                                                 const float* __restrict__ b2,
                                                 const float* __restrict__ resid,
                                                 float* __restrict__ out) {
  const int i = blockIdx.x * 256 + threadIdx.x;  // float4 index
  float4 a = ((const float4*)p0)[i];
  float4 b = ((const float4*)p1)[i];
  float4 r = ((const float4*)resid)[i];
  float4 bb = ((const float4*)b2)[i & 255];
  float4 o;
  o.x = a.x + b.x + r.x + bb.x;
  o.y = a.y + b.y + r.y + bb.y;
  o.z = a.z + b.z + r.z + bb.z;
  o.w = a.w + b.w + r.w + bb.w;
  ((float4*)out)[i] = o;
}

// -----------------------------------------------------------------------------
extern "C" void kernel_launch(void* const* d_in, const int* in_sizes, int n_in,
                              void* d_out, int out_size, void* d_ws, size_t ws_size,
                              hipStream_t stream) {
  const float* query  = (const float*)d_in[0];
  const float* pf     = (const float*)d_in[1];
  const float* lnq_g  = (const float*)d_in[2];
  const float* lnq_b  = (const float*)d_in[3];
  const float* lnkv_g = (const float*)d_in[4];
  const float* lnkv_b = (const float*)d_in[5];
  const float* Wq     = (const float*)d_in[6];
  const float* bq     = (const float*)d_in[7];
  const float* Wk     = (const float*)d_in[8];
  const float* bk     = (const float*)d_in[9];
  const float* Wv     = (const float*)d_in[10];
  const float* bv     = (const float*)d_in[11];
  const float* rmsq_g = (const float*)d_in[12];
  const float* rmsk_g = (const float*)d_in[13];
  const float* Wo     = (const float*)d_in[14];
  const float* bo     = (const float*)d_in[15];
  const float* mlpn_g = (const float*)d_in[16];
  const float* mlpn_b = (const float*)d_in[17];
  const float* W1     = (const float*)d_in[18];
  const float* b1     = (const float*)d_in[19];
  const float* W2     = (const float*)d_in[20];
  const float* b2     = (const float*)d_in[21];
  float* out = (float*)d_out;

  char* p = (char*)d_ws;
  auto alloc = [&](size_t n) {
    char* r = p;
    p += (n + 255) & ~(size_t)255;
    return r;
  };

  u16* Wqt = (u16*)alloc((size_t)1024 * 1024 * 2);
  u16* KVt = (u16*)alloc((size_t)2048 * 1024 * 2);  // [Wk^T ; Wv^T]
  u16* Wot = (u16*)alloc((size_t)1024 * 1024 * 2);
  u16* W1t = (u16*)alloc((size_t)1024 * 4096 * 2);
  u16* W2t = (u16*)alloc((size_t)4096 * 1024 * 2);
  u16* qln = (u16*)alloc((size_t)4096 * 1024 * 2);
  u16* qpre = (u16*)alloc((size_t)4096 * 1024 * 2);
  float* qssq = (float*)alloc((size_t)4096 * 4);
  u16* attn_o = (u16*)alloc((size_t)4096 * 1024 * 2);
  float* outbuf = (float*)alloc((size_t)4096 * 1024 * 4);
  u16* hbuf = (u16*)alloc((size_t)4096 * 1024 * 2);
  u16* mid = (u16*)alloc((size_t)4096 * 4096 * 2);
  float* w2p = (float*)alloc((size_t)2 * 4096 * 1024 * 4);  // split-K partials

  // chunked KV pipeline buffers (NC chunks; chunk data stays L3-resident)
  const size_t used = (size_t)(p - (char*)d_ws);
  int NC = 4;
  while (NC < 64) {
    size_t rows_try = (size_t)131072 / NC;
    if (used + 3 * (rows_try * 2048 + 256) + rows_try * 4 + 256 <= ws_size) break;
    NC *= 2;
  }
  const size_t rows = (size_t)131072 / NC;
  u16* kvln = (u16*)alloc(rows * 2048);
  u16* kmat = (u16*)alloc(rows * 2048);
  u16* vmat = (u16*)alloc(rows * 2048);
  float* kssq = (float*)alloc(rows * 4);

  // weight transpose+convert: W[K][N] f32 -> Wt[N][K] bf16
  transpose_w<<<dim3(32, 32), 256, 0, stream>>>(Wq, Wqt, 1024, 1024);
  transpose_w<<<dim3(32, 32), 256, 0, stream>>>(Wk, KVt, 1024, 1024);
  transpose_w<<<dim3(32, 32), 256, 0, stream>>>(Wv, KVt + (size_t)1024 * 1024, 1024, 1024);
  transpose_w<<<dim3(32, 32), 256, 0, stream>>>(Wo, Wot, 1024, 1024);
  transpose_w<<<dim3(128, 32), 256, 0, stream>>>(W1, W1t, 1024, 4096);
  transpose_w<<<dim3(32, 128), 256, 0, stream>>>(W2, W2t, 4096, 1024);

  // q path: LN -> GEMM(Wq)+bq (epilogue: bf16 qpre + qssq atomics)
  ln_rows<<<4096, 256, 0, stream>>>(query, lnq_g, lnq_b, qln, qssq);
  gemm_bt<5><<<dim3(8, 32), 256, 0, stream>>>(qln, Wqt, bq, nullptr, qpre, nullptr,
                                              qssq, 4096, 1024, 1024);

  // kv path: chunked ln -> fused K+V gemm256 -> attn (chunk stays in L3)
  const int bpc = 4096 / NC;
  const int RB = (int)(rows / 256);
  for (int c = 0; c < NC; ++c) {
    ln_rows<<<(unsigned)rows, 256, 0, stream>>>(pf + (size_t)c * rows * 1024, lnkv_g,
                                                lnkv_b, kvln, kssq);
    gemm256<0, 1024><<<RB * 8, 512, 0, stream>>>(kvln, KVt, bk, bv, rmsk_g, kmat, vmat,
                                                 kssq, (int)rows, 2048, RB, 8);
    attn_k<<<bpc, 256, 0, stream>>>(qpre + (size_t)c * bpc * 1024, kmat, kssq, vmat,
                                    rmsq_g, qssq + (size_t)c * bpc,
                                    attn_o + (size_t)c * bpc * 1024);
  }

  // out = attn_o @ Wo + bo + query  (f32)
  gemm_bt<3><<<dim3(8, 32), 256, 0, stream>>>(attn_o, Wot, bo, nullptr, outbuf, query,
                                              nullptr, 4096, 1024, 1024);
  // h = LN(out)
  ln_rows<<<4096, 256, 0, stream>>>(outbuf, mlpn_g, mlpn_b, hbuf, nullptr);
  // mid = gelu(h @ W1 + b1)  -- 256^2 kernel, grid 16x16
  gemm256<1, 1024><<<16 * 16, 512, 0, stream>>>(hbuf, W1t, b1, nullptr, nullptr, mid,
                                                nullptr, nullptr, 4096, 4096, 16, 16);
  // final = mid @ W2 (split-K=2 partials) + b2 + out
  gemm_bt<6><<<dim3(8, 32, 2), 256, 0, stream>>>(mid, W2t, nullptr, nullptr, w2p,
                                                 nullptr, nullptr, 4096, 1024, 4096);
  combine_k<<<4096, 256, 0, stream>>>(w2p, w2p + (size_t)4096 * 1024, b2, outbuf, out);
}

// Round 12
// 1076.658 us; speedup vs baseline: 1.0089x; 1.0089x over previous
//
#include <hip/hip_runtime.h>
#include <stdint.h>

#define DEVI __device__ __forceinline__

typedef unsigned short u16;
typedef short s8v __attribute__((ext_vector_type(8)));
typedef float f4v __attribute__((ext_vector_type(4)));
typedef u16 u16x4 __attribute__((ext_vector_type(4)));

DEVI u16 f2bf(float f) {
  unsigned u = __float_as_uint(f);
  u += 0x7fffu + ((u >> 16) & 1u);
  return (u16)(u >> 16);
}
DEVI float bf2f(u16 h) { return __uint_as_float(((unsigned)h) << 16); }

DEVI void gload16(const void* g, void* l) {
  __builtin_amdgcn_global_load_lds(
      (const __attribute__((address_space(1))) void*)(uintptr_t)g,
      (__attribute__((address_space(3))) void*)(uintptr_t)l, 16, 0, 0);
}

// ---------------- transpose + f32->bf16 convert: W[R][C] -> Wt[C][R] ----------
__global__ __launch_bounds__(256) void transpose_w(const float* __restrict__ W,
                                                   u16* __restrict__ Wt, int R, int C) {
  __shared__ float tile[32][33];
  const int tx = threadIdx.x & 31, ty = threadIdx.x >> 5;
  const int r0 = blockIdx.y * 32, c0 = blockIdx.x * 32;
#pragma unroll
  for (int i = 0; i < 4; ++i)
    tile[ty + 8 * i][tx] = W[(size_t)(r0 + ty + 8 * i) * C + c0 + tx];
  __syncthreads();
#pragma unroll
  for (int i = 0; i < 4; ++i)
    Wt[(size_t)(c0 + ty + 8 * i) * R + r0 + tx] = f2bf(tile[tx][ty + 8 * i]);
}

// ------- row LayerNorm (D=1024), f32 in -> bf16 out; optionally zero zbuf[row]
__global__ __launch_bounds__(256) void ln_rows(const float* __restrict__ x,
                                               const float* __restrict__ g,
                                               const float* __restrict__ bsh,
                                               u16* __restrict__ y,
                                               float* __restrict__ zbuf) {
  const size_t row = blockIdx.x;
  const int t = threadIdx.x;
  if (zbuf && t == 0) zbuf[row] = 0.f;
  float4 v = ((const float4*)(x + row * 1024))[t];
  float s = v.x + v.y + v.z + v.w;
  float q = v.x * v.x + v.y * v.y + v.z * v.z + v.w * v.w;
#pragma unroll
  for (int m = 1; m < 64; m <<= 1) { s += __shfl_xor(s, m); q += __shfl_xor(q, m); }
  __shared__ float sh[8];
  if ((t & 63) == 0) { sh[t >> 6] = s; sh[4 + (t >> 6)] = q; }
  __syncthreads();
  s = sh[0] + sh[1] + sh[2] + sh[3];
  q = sh[4] + sh[5] + sh[6] + sh[7];
  const float mu = s * (1.f / 1024.f);
  const float var = q * (1.f / 1024.f) - mu * mu;
  const float rs = rsqrtf(var + 1e-5f);
  const int c = t * 4;
  const float in[4] = {v.x, v.y, v.z, v.w};
  u16x4 o;
#pragma unroll
  for (int i = 0; i < 4; ++i) o[i] = f2bf((in[i] - mu) * rs * g[c + i] + bsh[c + i]);
  *(u16x4*)(y + row * 1024 + c) = o;
}

// ====== 256x256 MFMA GEMM, BK=32, 2-slot dbuf (64KB LDS -> 2 blocks/CU) ======
// Occupancy lever: all prior variants used 128KB LDS = 1 block/CU, so barrier
// stalls idled the whole CU.  64KB => TWO independent blocks/CU (VGPR=100
// permits 16 waves); one block's stage/barrier phases are filled by the
// other's ds_read/MFMA stream (m114/m97 TLP mechanism).
// Per iter T (SL=T&1, SN=(T+1)&1):
//   barrier1  -- slot SN's readers (tile T-1) done (reads lgkm-consumed before
//                each wave's iter-T-1 MFMAs, hence before this barrier)
//   stage tile T+1 -> slot SN (4 gloads; clamped tail => uniform 4/iter)
//   vmcnt(4)  -- issued=4(T+2); completed >= 4(T+1) => tile T resident (own
//                loads, issued one full tile earlier)
//   barrier2  -- collective residency
//   12 ds_read_b128 (a[8],b[4]) ; setprio1 ; 32 MFMA ; setprio0
// Swizzle: LDS chunk c of row r holds global k-chunk c^((r>>1)&3); write =
// linear dest + pre-swizzled global col; read kx = (kq^((fr>>1)&3))*16B.
// (identical scheme to R3-R8, verified SQ_LDS_BANK_CONFLICT = 0)
// EPI 0: fused KV epilogue (col0<1024 -> K-path w/ rowssq+gain, else V-path)
// EPI 1: CK bf16 = gelu_exact(acc + biasK[col]), ldc = N.
template <int EPI, int KK>
__global__ __launch_bounds__(512, 2) void gemm256(
    const u16* __restrict__ A, const u16* __restrict__ Bt,
    const float* __restrict__ biasK, const float* __restrict__ biasV,
    const float* __restrict__ gcol, u16* __restrict__ CK, u16* __restrict__ CV,
    float* __restrict__ rowssq, int M, int N, int RB, int CB) {
  __shared__ u16 lds[2][16384];  // slot: A [256][32] (16KB) + B [256][32] (16KB)
  const int t = threadIdx.x;
  const int lane = t & 63;
  const int wave = t >> 6;
  const int wm = wave >> 2, wn = wave & 3;
  const int fr = lane & 15, kq = lane >> 4;

  const int bid = blockIdx.x;
  const int cpx = gridDim.x >> 3;
  const int swz = (bid & 7) * cpx + (bid >> 3);
  const int rb = swz / CB, cb = swz % CB;  // cb-fastest
  const size_t row0 = (size_t)rb * 256, col0 = (size_t)cb * 256;

  f4v acc[8][4];
#pragma unroll
  for (int i = 0; i < 8; ++i)
#pragma unroll
    for (int n = 0; n < 4; ++n) acc[i][n] = (f4v){0.f, 0.f, 0.f, 0.f};

  // staging: thread t -> row t>>2 (+128 for 2nd load), LDS linear dest t*16B,
  // global chunk pre-swizzled: (t&3) ^ ((t>>3)&3) == (t&3) ^ ((srow>>1)&3)
  const int srow = t >> 2;
  const int scol = (((t & 3) ^ ((t >> 3) & 3)) << 3);
  const u16* Ag = A + (row0 + srow) * (size_t)KK + scol;
  const u16* Bg = Bt + (col0 + srow) * (size_t)KK + scol;
  char* dA[2];
  char* dB[2];
  const char* lb = (const char*)&lds[0][0];
#pragma unroll
  for (int s = 0; s < 2; ++s) {
    dA[s] = (char*)lb + s * 32768 + t * 16;
    dB[s] = (char*)lb + s * 32768 + 16384 + t * 16;
  }

  // read bases: A frag i -> row wm*128+i*16+fr; B frag n -> row wn*64+n*16+fr
  const int kxb = ((kq ^ ((fr >> 1) & 3)) << 4);  // swizzled chunk byte offset
  const char* bA[2];
  const char* bB[2];
#pragma unroll
  for (int s = 0; s < 2; ++s) {
    bA[s] = lb + s * 32768 + (wm * 128 + fr) * 64 + kxb;
    bB[s] = lb + s * 32768 + 16384 + (wn * 64 + fr) * 64 + kxb;
  }

  const int NT = KK >> 5;  // BK=32; 32 for KK=1024 (even)

  // prologue: stage tile 0 into slot 0 (4 loads)
  gload16(Ag, dA[0]);
  gload16(Ag + (size_t)128 * KK, dA[0] + 8192);
  gload16(Bg, dB[0]);
  gload16(Bg + (size_t)128 * KK, dB[0] + 8192);

#define KV_ITER(T_, SL, SN)                                                      \
  {                                                                              \
    __builtin_amdgcn_s_barrier(); /* slot SN readers (tile T-1) done */          \
    const int Ts = (T_ + 1 < NT) ? T_ + 1 : NT - 1;                              \
    const u16* Agt = Ag + (size_t)Ts * 32;                                       \
    const u16* Bgt = Bg + (size_t)Ts * 32;                                       \
    gload16(Agt, dA[SN]);                                                        \
    gload16(Agt + (size_t)128 * KK, dA[SN] + 8192);                              \
    gload16(Bgt, dB[SN]);                                                        \
    gload16(Bgt + (size_t)128 * KK, dB[SN] + 8192);                              \
    asm volatile("s_waitcnt vmcnt(4)" ::: "memory"); /* tile T landed */         \
    __builtin_amdgcn_s_barrier();                    /* collective residency */  \
    s8v a[8], b[4];                                                              \
    _Pragma("unroll") for (int i = 0; i < 8; ++i)                                \
        a[i] = *(const s8v*)(bA[SL] + i * 1024);                                 \
    _Pragma("unroll") for (int n = 0; n < 4; ++n)                                \
        b[n] = *(const s8v*)(bB[SL] + n * 1024);                                 \
    __builtin_amdgcn_s_setprio(1);                                               \
    _Pragma("unroll") for (int i = 0; i < 8; ++i)                                \
        _Pragma("unroll") for (int n = 0; n < 4; ++n)                            \
            acc[i][n] =                                                          \
        __builtin_amdgcn_mfma_f32_16x16x32_bf16(a[i], b[n], acc[i][n], 0, 0, 0); \
    __builtin_amdgcn_s_setprio(0);                                               \
  }

  for (int T = 0; T < NT; T += 2) {
    KV_ITER(T, 0, 1);
    KV_ITER((T + 1), 1, 0);
  }
#undef KV_ITER

  // ---- epilogue ----
  const int kq4 = kq * 4;
  if (EPI == 0) {
    const bool isK = (col0 < 1024);
    if (isK) {
#pragma unroll
      for (int ai = 0; ai < 8; ++ai) {
        int cols[4];
        float bb[4], gg[4];
#pragma unroll
        for (int n = 0; n < 4; ++n) {
          cols[n] = (int)col0 + wn * 64 + n * 16 + fr;
          bb[n] = biasK[cols[n]];
          gg[n] = gcol[cols[n]];
        }
#pragma unroll
        for (int r = 0; r < 4; ++r) {
          const size_t grow = row0 + wm * 128 + ai * 16 + kq4 + r;
          float v[4];
#pragma unroll
          for (int n = 0; n < 4; ++n) v[n] = acc[ai][n][r] + bb[n];
          float s = v[0] * v[0] + v[1] * v[1] + v[2] * v[2] + v[3] * v[3];
          s += __shfl_xor(s, 1);
          s += __shfl_xor(s, 2);
          s += __shfl_xor(s, 4);
          s += __shfl_xor(s, 8);
          if (fr == 0) atomicAdd(&rowssq[grow], s);
#pragma unroll
          for (int n = 0; n < 4; ++n)
            CK[grow * 1024 + cols[n]] = f2bf(v[n] * gg[n]);
        }
      }
    } else {
#pragma unroll
      for (int ai = 0; ai < 8; ++ai) {
        int cols[4];
        float bb[4];
#pragma unroll
        for (int n = 0; n < 4; ++n) {
          cols[n] = (int)col0 - 1024 + wn * 64 + n * 16 + fr;
          bb[n] = biasV[cols[n]];
        }
#pragma unroll
        for (int r = 0; r < 4; ++r) {
          const size_t grow = row0 + wm * 128 + ai * 16 + kq4 + r;
#pragma unroll
          for (int n = 0; n < 4; ++n)
            CV[grow * 1024 + cols[n]] = f2bf(acc[ai][n][r] + bb[n]);
        }
      }
    }
  } else {
#pragma unroll
    for (int ai = 0; ai < 8; ++ai) {
      int cols[4];
      float bb[4];
#pragma unroll
      for (int n = 0; n < 4; ++n) {
        cols[n] = (int)col0 + wn * 64 + n * 16 + fr;
        bb[n] = biasK[cols[n]];
      }
#pragma unroll
      for (int r = 0; r < 4; ++r) {
        const size_t grow = row0 + wm * 128 + ai * 16 + kq4 + r;
#pragma unroll
        for (int n = 0; n < 4; ++n) {
          const float x = acc[ai][n][r] + bb[n];
          CK[grow * (size_t)N + cols[n]] = f2bf(0.5f * x * (1.f + erff(x * 0.70710678118654752f)));
        }
      }
    }
  }
}

// ---------------- 128x128 MFMA GEMM (m97 structure), epilogues ---------------
// EPI 3: store f32 (acc+bias+extra[row,col])
// EPI 5: v=acc+bias; atomic rowssq += v^2; store bf16 v   (q-path)
// EPI 6: split-K partial: store f32 raw acc to Cv + z*M*N; K-range by blockIdx.z
template <int EPI>
__global__ __launch_bounds__(256) void gemm_bt(
    const u16* __restrict__ A, const u16* __restrict__ Bt,
    const float* __restrict__ bias, const float* __restrict__ gcol,
    void* __restrict__ Cv, const float* __restrict__ extra,
    float* __restrict__ rowssq, int M, int N, int K) {
  __shared__ u16 As[128 * 32];
  __shared__ u16 Bs[128 * 32];
  const int t = threadIdx.x;
  const int lane = t & 63;
  const int wave = t >> 6;
  const int wr = wave >> 1, wc = wave & 1;
  const size_t row0 = (size_t)blockIdx.y * 128;
  const size_t col0 = (size_t)blockIdx.x * 128;
  int Ksub = K, koff = 0;
  if (EPI == 6) { Ksub = K / gridDim.z; koff = blockIdx.z * Ksub; }

  f4v acc[4][4];
#pragma unroll
  for (int m = 0; m < 4; ++m)
#pragma unroll
    for (int n = 0; n < 4; ++n) acc[m][n] = (f4v){0.f, 0.f, 0.f, 0.f};

  const int sr = t >> 2;
  const int scw = (((t & 3) ^ ((t >> 3) & 3)) << 3);  // pre-swizzled global col
  const u16* Ag = A + (row0 + sr) * (size_t)K + koff + scw;
  const u16* Bg = Bt + (col0 + sr) * (size_t)K + koff + scw;
  u16* Al = &As[t * 8];  // linear dest
  u16* Bl = &Bs[t * 8];
  const int fr = lane & 15;
  const int kx = (((lane >> 4) ^ ((fr >> 1) & 3)) << 3);

  for (int k0 = 0; k0 < Ksub; k0 += 32) {
    gload16(Ag + k0, Al);
    gload16(Ag + k0 + (size_t)64 * K, Al + 64 * 32);
    gload16(Bg + k0, Bl);
    gload16(Bg + k0 + (size_t)64 * K, Bl + 64 * 32);
    __syncthreads();
    s8v a[4], b[4];
#pragma unroll
    for (int m = 0; m < 4; ++m)
      a[m] = *(const s8v*)&As[(wr * 64 + m * 16 + fr) * 32 + kx];
#pragma unroll
    for (int n = 0; n < 4; ++n)
      b[n] = *(const s8v*)&Bs[(wc * 64 + n * 16 + fr) * 32 + kx];
#pragma unroll
    for (int m = 0; m < 4; ++m)
#pragma unroll
      for (int n = 0; n < 4; ++n)
        acc[m][n] = __builtin_amdgcn_mfma_f32_16x16x32_bf16(a[m], b[n], acc[m][n], 0, 0, 0);
    __syncthreads();
  }

  float* Cp = (float*)Cv;
  if (EPI == 6) Cp += (size_t)blockIdx.z * M * (size_t)N;
  const int rg = (lane >> 4) * 4;
#pragma unroll
  for (int m = 0; m < 4; ++m) {
    int cols[4];
    float bvals[4];
#pragma unroll
    for (int n = 0; n < 4; ++n) {
      cols[n] = (int)col0 + wc * 64 + n * 16 + fr;
      bvals[n] = (EPI == 6) ? 0.f : bias[cols[n]];
    }
#pragma unroll
    for (int r = 0; r < 4; ++r) {
      const size_t grow = row0 + wr * 64 + m * 16 + rg + r;
      float v[4];
#pragma unroll
      for (int n = 0; n < 4; ++n) v[n] = acc[m][n][r] + bvals[n];
      if (EPI == 5) {
        float s = v[0] * v[0] + v[1] * v[1] + v[2] * v[2] + v[3] * v[3];
        s += __shfl_xor(s, 1);
        s += __shfl_xor(s, 2);
        s += __shfl_xor(s, 4);
        s += __shfl_xor(s, 8);
        if (fr == 0) atomicAdd(&rowssq[grow], s);
      }
#pragma unroll
      for (int n = 0; n < 4; ++n) {
        const size_t idx = grow * (size_t)N + cols[n];
        if (EPI == 3) {
          Cp[idx] = v[n] + extra[idx];
        } else if (EPI == 5) {
          ((u16*)Cv)[idx] = f2bf(v[n]);
        } else if (EPI == 6) {
          Cp[idx] = v[n];
        }
      }
    }
  }
}

// ---------------- attention with the faithful raw-reshape semantics ----------
// head h, key j in [0,32): kv position = 2h + j/16, d-slice = (j%16)*64 .. +64
// q applied here: q_eff[d] = qpre[d]*gq[d]*rsq_q*0.125 (rms of q folded)
__global__ __launch_bounds__(256) void attn_k(const u16* __restrict__ qf,
                                              const u16* __restrict__ kmat,
                                              const float* __restrict__ kssq,
                                              const u16* __restrict__ vmat,
                                              const float* __restrict__ gq,
                                              const float* __restrict__ qssq,
                                              u16* __restrict__ ao) {
  const int lb = blockIdx.x;
  const int t = threadIdx.x;
  const int wave = t >> 6, lane = t & 63;
  const int j = lane & 31, half = lane >> 5;
  const float rq = rsqrtf(qssq[lb] * (1.f / 1024.f) + 1e-6f) * 0.125f;
  __shared__ float po[64][17];
#pragma unroll
  for (int hi = 0; hi < 4; ++hi) {
    const int h = wave * 4 + hi;
    const int krow = lb * 32 + 2 * h + (j >> 4);
    const u16* kp = kmat + (size_t)krow * 1024 + (j & 15) * 64 + half * 32;
    const u16* qp = qf + (size_t)lb * 1024 + h * 64 + half * 32;
    const float* gqp = gq + h * 64 + half * 32;
    float s = 0.f;
#pragma unroll
    for (int cc = 0; cc < 4; ++cc) {
      s8v qv = *(const s8v*)(qp + cc * 8);
      s8v kv = *(const s8v*)(kp + cc * 8);
#pragma unroll
      for (int e = 0; e < 8; ++e)
        s += bf2f((u16)qv[e]) * gqp[cc * 8 + e] * bf2f((u16)kv[e]);
    }
    s += __shfl_xor(s, 32);
    s *= rsqrtf(kssq[krow] * (1.f / 1024.f) + 1e-6f) * rq;
    float mx = s;
#pragma unroll
    for (int m = 16; m >= 1; m >>= 1) mx = fmaxf(mx, __shfl_xor(mx, m));
    const float pe = __expf(s - mx);
    float sum = pe;
#pragma unroll
    for (int m = 16; m >= 1; m >>= 1) sum += __shfl_xor(sum, m);
    const float pr = pe / sum;
    float o = 0.f;
#pragma unroll
    for (int jj = 0; jj < 32; ++jj) {
      const int vrow = lb * 32 + 2 * h + (jj >> 4);
      const float vv = bf2f(vmat[(size_t)vrow * 1024 + (jj & 15) * 64 + lane]);
      o += __shfl(pr, jj) * vv;
    }
    po[lane][h] = o;  // hd = lane
  }
  __syncthreads();
  const int c = t * 4;
  u16x4 o4;
#pragma unroll
  for (int i = 0; i < 4; ++i) o4[i] = f2bf(po[(c + i) >> 4][(c + i) & 15]);
  *(u16x4*)(ao + (size_t)lb * 1024 + c) = o4;
}

// ------------- W2 split-K combine: out = p0 + p1 + b2[col] + resid -----------
__global__ __launch_bounds__(256) void combine_k(const float* __restrict__ p0,
                                                 const float* __restrict__ p1,
                                                 const float* __restrict__ b2,
                                                 const float* __restrict__ resid,
                                                 float* __restrict__ out) {
  const int i = blockIdx.x * 256 + threadIdx.x;  // float4 index
  float4 a = ((const float4*)p0)[i];
  float4 b = ((const float4*)p1)[i];
  float4 r = ((const float4*)resid)[i];
  float4 bb = ((const float4*)b2)[i & 255];
  float4 o;
  o.x = a.x + b.x + r.x + bb.x;
  o.y = a.y + b.y + r.y + bb.y;
  o.z = a.z + b.z + r.z + bb.z;
  o.w = a.w + b.w + r.w + bb.w;
  ((float4*)out)[i] = o;
}

// -----------------------------------------------------------------------------
extern "C" void kernel_launch(void* const* d_in, const int* in_sizes, int n_in,
                              void* d_out, int out_size, void* d_ws, size_t ws_size,
                              hipStream_t stream) {
  const float* query  = (const float*)d_in[0];
  const float* pf     = (const float*)d_in[1];
  const float* lnq_g  = (const float*)d_in[2];
  const float* lnq_b  = (const float*)d_in[3];
  const float* lnkv_g = (const float*)d_in[4];
  const float* lnkv_b = (const float*)d_in[5];
  const float* Wq     = (const float*)d_in[6];
  const float* bq     = (const float*)d_in[7];
  const float* Wk     = (const float*)d_in[8];
  const float* bk     = (const float*)d_in[9];
  const float* Wv     = (const float*)d_in[10];
  const float* bv     = (const float*)d_in[11];
  const float* rmsq_g = (const float*)d_in[12];
  const float* rmsk_g = (const float*)d_in[13];
  const float* Wo     = (const float*)d_in[14];
  const float* bo     = (const float*)d_in[15];
  const float* mlpn_g = (const float*)d_in[16];
  const float* mlpn_b = (const float*)d_in[17];
  const float* W1     = (const float*)d_in[18];
  const float* b1     = (const float*)d_in[19];
  const float* W2     = (const float*)d_in[20];
  const float* b2     = (const float*)d_in[21];
  float* out = (float*)d_out;

  char* p = (char*)d_ws;
  auto alloc = [&](size_t n) {
    char* r = p;
    p += (n + 255) & ~(size_t)255;
    return r;
  };

  u16* Wqt = (u16*)alloc((size_t)1024 * 1024 * 2);
  u16* KVt = (u16*)alloc((size_t)2048 * 1024 * 2);  // [Wk^T ; Wv^T]
  u16* Wot = (u16*)alloc((size_t)1024 * 1024 * 2);
  u16* W1t = (u16*)alloc((size_t)1024 * 4096 * 2);
  u16* W2t = (u16*)alloc((size_t)4096 * 1024 * 2);
  u16* qln = (u16*)alloc((size_t)4096 * 1024 * 2);
  u16* qpre = (u16*)alloc((size_t)4096 * 1024 * 2);
  float* qssq = (float*)alloc((size_t)4096 * 4);
  u16* attn_o = (u16*)alloc((size_t)4096 * 1024 * 2);
  float* outbuf = (float*)alloc((size_t)4096 * 1024 * 4);
  u16* hbuf = (u16*)alloc((size_t)4096 * 1024 * 2);
  u16* mid = (u16*)alloc((size_t)4096 * 4096 * 2);
  float* w2p = (float*)alloc((size_t)2 * 4096 * 1024 * 4);  // split-K partials

  // chunked KV pipeline buffers (NC chunks; chunk data stays L3-resident)
  const size_t used = (size_t)(p - (char*)d_ws);
  int NC = 4;
  while (NC < 64) {
    size_t rows_try = (size_t)131072 / NC;
    if (used + 3 * (rows_try * 2048 + 256) + rows_try * 4 + 256 <= ws_size) break;
    NC *= 2;
  }
  const size_t rows = (size_t)131072 / NC;
  u16* kvln = (u16*)alloc(rows * 2048);
  u16* kmat = (u16*)alloc(rows * 2048);
  u16* vmat = (u16*)alloc(rows * 2048);
  float* kssq = (float*)alloc(rows * 4);

  // weight transpose+convert: W[K][N] f32 -> Wt[N][K] bf16
  transpose_w<<<dim3(32, 32), 256, 0, stream>>>(Wq, Wqt, 1024, 1024);
  transpose_w<<<dim3(32, 32), 256, 0, stream>>>(Wk, KVt, 1024, 1024);
  transpose_w<<<dim3(32, 32), 256, 0, stream>>>(Wv, KVt + (size_t)1024 * 1024, 1024, 1024);
  transpose_w<<<dim3(32, 32), 256, 0, stream>>>(Wo, Wot, 1024, 1024);
  transpose_w<<<dim3(128, 32), 256, 0, stream>>>(W1, W1t, 1024, 4096);
  transpose_w<<<dim3(32, 128), 256, 0, stream>>>(W2, W2t, 4096, 1024);

  // q path: LN -> GEMM(Wq)+bq (epilogue: bf16 qpre + qssq atomics)
  ln_rows<<<4096, 256, 0, stream>>>(query, lnq_g, lnq_b, qln, qssq);
  gemm_bt<5><<<dim3(8, 32), 256, 0, stream>>>(qln, Wqt, bq, nullptr, qpre, nullptr,
                                              qssq, 4096, 1024, 1024);

  // kv path: chunked ln -> fused K+V gemm256 -> attn (chunk stays in L3)
  const int bpc = 4096 / NC;
  const int RB = (int)(rows / 256);
  for (int c = 0; c < NC; ++c) {
    ln_rows<<<(unsigned)rows, 256, 0, stream>>>(pf + (size_t)c * rows * 1024, lnkv_g,
                                                lnkv_b, kvln, kssq);
    gemm256<0, 1024><<<RB * 8, 512, 0, stream>>>(kvln, KVt, bk, bv, rmsk_g, kmat, vmat,
                                                 kssq, (int)rows, 2048, RB, 8);
    attn_k<<<bpc, 256, 0, stream>>>(qpre + (size_t)c * bpc * 1024, kmat, kssq, vmat,
                                    rmsq_g, qssq + (size_t)c * bpc,
                                    attn_o + (size_t)c * bpc * 1024);
  }

  // out = attn_o @ Wo + bo + query  (f32)
  gemm_bt<3><<<dim3(8, 32), 256, 0, stream>>>(attn_o, Wot, bo, nullptr, outbuf, query,
                                              nullptr, 4096, 1024, 1024);
  // h = LN(out)
  ln_rows<<<4096, 256, 0, stream>>>(outbuf, mlpn_g, mlpn_b, hbuf, nullptr);
  // mid = gelu(h @ W1 + b1)  -- 256^2 kernel, grid 16x16
  gemm256<1, 1024><<<16 * 16, 512, 0, stream>>>(hbuf, W1t, b1, nullptr, nullptr, mid,
                                                nullptr, nullptr, 4096, 4096, 16, 16);
  // final = mid @ W2 (split-K=2 partials) + b2 + out
  gemm_bt<6><<<dim3(8, 32, 2), 256, 0, stream>>>(mid, W2t, nullptr, nullptr, w2p,
                                                 nullptr, nullptr, 4096, 1024, 4096);
  combine_k<<<4096, 256, 0, stream>>>(w2p, w2p + (size_t)4096 * 1024, b2, outbuf, out);
}

// Round 13
// 1031.287 us; speedup vs baseline: 1.0533x; 1.0440x over previous
//
#include <hip/hip_runtime.h>
#include <stdint.h>

#define DEVI __device__ __forceinline__

typedef unsigned short u16;
typedef short s8v __attribute__((ext_vector_type(8)));
typedef float f4v __attribute__((ext_vector_type(4)));
typedef u16 u16x4 __attribute__((ext_vector_type(4)));

DEVI u16 f2bf(float f) {
  unsigned u = __float_as_uint(f);
  u += 0x7fffu + ((u >> 16) & 1u);
  return (u16)(u >> 16);
}
DEVI float bf2f(u16 h) { return __uint_as_float(((unsigned)h) << 16); }

DEVI void gload16(const void* g, void* l) {
  __builtin_amdgcn_global_load_lds(
      (const __attribute__((address_space(1))) void*)(uintptr_t)g,
      (__attribute__((address_space(3))) void*)(uintptr_t)l, 16, 0, 0);
}

// ---------------- transpose + f32->bf16 convert: W[R][C] -> Wt[C][R] ----------
__global__ __launch_bounds__(256) void transpose_w(const float* __restrict__ W,
                                                   u16* __restrict__ Wt, int R, int C) {
  __shared__ float tile[32][33];
  const int tx = threadIdx.x & 31, ty = threadIdx.x >> 5;
  const int r0 = blockIdx.y * 32, c0 = blockIdx.x * 32;
#pragma unroll
  for (int i = 0; i < 4; ++i)
    tile[ty + 8 * i][tx] = W[(size_t)(r0 + ty + 8 * i) * C + c0 + tx];
  __syncthreads();
#pragma unroll
  for (int i = 0; i < 4; ++i)
    Wt[(size_t)(c0 + ty + 8 * i) * R + r0 + tx] = f2bf(tile[tx][ty + 8 * i]);
}

// ------- row LayerNorm (D=1024), f32 in -> bf16 out; optionally zero zbuf[row]
__global__ __launch_bounds__(256) void ln_rows(const float* __restrict__ x,
                                               const float* __restrict__ g,
                                               const float* __restrict__ bsh,
                                               u16* __restrict__ y,
                                               float* __restrict__ zbuf) {
  const size_t row = blockIdx.x;
  const int t = threadIdx.x;
  if (zbuf && t == 0) zbuf[row] = 0.f;
  float4 v = ((const float4*)(x + row * 1024))[t];
  float s = v.x + v.y + v.z + v.w;
  float q = v.x * v.x + v.y * v.y + v.z * v.z + v.w * v.w;
#pragma unroll
  for (int m = 1; m < 64; m <<= 1) { s += __shfl_xor(s, m); q += __shfl_xor(q, m); }
  __shared__ float sh[8];
  if ((t & 63) == 0) { sh[t >> 6] = s; sh[4 + (t >> 6)] = q; }
  __syncthreads();
  s = sh[0] + sh[1] + sh[2] + sh[3];
  q = sh[4] + sh[5] + sh[6] + sh[7];
  const float mu = s * (1.f / 1024.f);
  const float var = q * (1.f / 1024.f) - mu * mu;
  const float rs = rsqrtf(var + 1e-5f);
  const int c = t * 4;
  const float in[4] = {v.x, v.y, v.z, v.w};
  u16x4 o;
#pragma unroll
  for (int i = 0; i < 4; ++i) o[i] = f2bf((in[i] - mu) * rs * g[c + i] + bsh[c + i]);
  *(u16x4*)(y + row * 1024 + c) = o;
}

// ====== 256x256 MFMA GEMM, BK=64, 2-slot dbuf, 4 phases/tile (R9 = best) =====
// Best-measured configuration across 9 structural variants (R3-R12).  Per
// K-tile (64): 4 phases {ds_read quadrant | 2 gload_lds (1/4 of tile T+1) |
// setprio1 | 16 MFMA | setprio0}, no mid-tile fences (plain-C++ reads ->
// compiler counted lgkm waits); ONE {vmcnt(0); s_barrier; sched_barrier(0)}
// per tile (drain is semantically required: phase-0 reads of tile T+1 touch
// quarters staged last in program order, and staging order is wave-uniform).
// Slot safety: stage targets slot (T+1)&1 whose tile T-1 reads finished
// before the top-of-T fence.  Tail: clamped restage of tile NT-1 into the
// dead slot keeps per-wave issue counts uniform.
// Swizzle (128-B rows): LDS[r][chunk c] holds global k-chunk c^(r&7).
// Write: linear LDS dest + pre-swizzled global col ((t&7)^((t>>3)&7))*8.
// Read: chunk byte-offsets kx0 = ((kq^(fr&7))<<4), kx1 = kx0^64.
// (scheme verified SQ_LDS_BANK_CONFLICT = 0 in R4's profile)
// EPI 0: fused KV epilogue (col0<1024 -> K-path w/ rowssq+gain, else V-path)
// EPI 1: CK bf16 = gelu_exact(acc + biasK[col]), ldc = N.
template <int EPI, int KK>
__global__ __launch_bounds__(512, 2) void gemm256(
    const u16* __restrict__ A, const u16* __restrict__ Bt,
    const float* __restrict__ biasK, const float* __restrict__ biasV,
    const float* __restrict__ gcol, u16* __restrict__ CK, u16* __restrict__ CV,
    float* __restrict__ rowssq, int M, int N, int RB, int CB) {
  __shared__ u16 lds[2][32768];  // slot: A [256][64] (32KB) then B [256][64]
  const int t = threadIdx.x;
  const int lane = t & 63;
  const int wave = t >> 6;
  const int wm = wave >> 2, wn = wave & 3;
  const int fr = lane & 15, kq = lane >> 4;

  const int bid = blockIdx.x;
  const int cpx = gridDim.x >> 3;
  const int swz = (bid & 7) * cpx + (bid >> 3);
  const int rb = swz / CB, cb = swz % CB;  // cb-fastest
  const size_t row0 = (size_t)rb * 256, col0 = (size_t)cb * 256;

  f4v acc[8][4];
#pragma unroll
  for (int i = 0; i < 8; ++i)
#pragma unroll
    for (int n = 0; n < 4; ++n) acc[i][n] = (f4v){0.f, 0.f, 0.f, 0.f};

  // stage addressing: thread t -> row (t>>3)+j*64, LDS chunk t&7 (linear dest),
  // global chunk pre-swizzled
  const int srow = t >> 3;
  const int scol = (((t & 7) ^ (srow & 7)) << 3);
  const u16* Ag = A + (row0 + srow) * (size_t)KK + scol;
  const u16* Bg = Bt + (col0 + srow) * (size_t)KK + scol;
  char* dA[2];
  char* dB[2];
  const char* lb = (const char*)&lds[0][0];
#pragma unroll
  for (int s = 0; s < 2; ++s) {
    dA[s] = (char*)lb + s * 65536 + t * 16;
    dB[s] = (char*)lb + s * 65536 + 32768 + t * 16;
  }

  // read bases: A row = wm*128 + mh*64 + m*16 + fr; B row = wn*64 + nh*32 + n*16 + fr
  const int f7 = fr & 7;
  const int kx0 = ((kq ^ f7) << 4);
  const int kx1 = kx0 ^ 64;
  const char* bA[2][2];
  const char* bB[2][2];
#pragma unroll
  for (int s = 0; s < 2; ++s) {
    bA[s][0] = lb + s * 65536 + (wm * 128 + fr) * 128 + kx0;
    bA[s][1] = lb + s * 65536 + (wm * 128 + fr) * 128 + kx1;
    bB[s][0] = lb + s * 65536 + 32768 + (wn * 64 + fr) * 128 + kx0;
    bB[s][1] = lb + s * 65536 + 32768 + (wn * 64 + fr) * 128 + kx1;
  }

  const int NT = KK >> 6;  // BK=64; even for KK=1024 (16)

  // prologue: stage tile 0 into slot 0 (8 gloads: A quarters then B quarters)
#pragma unroll
  for (int j = 0; j < 4; ++j) {
    gload16(Ag + (size_t)j * 64 * KK, dA[0] + j * 8192);
    gload16(Bg + (size_t)j * 64 * KK, dB[0] + j * 8192);
  }
  asm volatile("s_waitcnt vmcnt(0)" ::: "memory");
  __builtin_amdgcn_s_barrier();
  __builtin_amdgcn_sched_barrier(0);

#define KV_ITER(T_, SL, SN)                                                      \
  {                                                                              \
    const int Ts = (T_ + 1 < NT) ? T_ + 1 : NT - 1;                              \
    const u16* Agt = Ag + (size_t)Ts * 64;                                       \
    const u16* Bgt = Bg + (size_t)Ts * 64;                                       \
    s8v a[8], b0[4], b1[4];                                                      \
    /* ---- ph0: quadrant (mh0,nh0) ---- */                                      \
    _Pragma("unroll") for (int m = 0; m < 4; ++m) {                              \
      a[2 * m] = *(const s8v*)(bA[SL][0] + m * 2048);                            \
      a[2 * m + 1] = *(const s8v*)(bA[SL][1] + m * 2048);                        \
    }                                                                            \
    _Pragma("unroll") for (int n = 0; n < 2; ++n) {                              \
      b0[2 * n] = *(const s8v*)(bB[SL][0] + n * 2048);                           \
      b0[2 * n + 1] = *(const s8v*)(bB[SL][1] + n * 2048);                       \
    }                                                                            \
    gload16(Agt, dA[SN]);                                                        \
    gload16(Agt + (size_t)64 * KK, dA[SN] + 8192);                               \
    __builtin_amdgcn_s_setprio(1);                                               \
    _Pragma("unroll") for (int m = 0; m < 4; ++m)                                \
        _Pragma("unroll") for (int n = 0; n < 2; ++n) {                          \
      acc[m][n] = __builtin_amdgcn_mfma_f32_16x16x32_bf16(a[2 * m], b0[2 * n],   \
                                                          acc[m][n], 0, 0, 0);   \
      acc[m][n] = __builtin_amdgcn_mfma_f32_16x16x32_bf16(                       \
          a[2 * m + 1], b0[2 * n + 1], acc[m][n], 0, 0, 0);                      \
    }                                                                            \
    __builtin_amdgcn_s_setprio(0);                                               \
    /* ---- ph1: quadrant (mh0,nh1) ---- */                                      \
    _Pragma("unroll") for (int n = 0; n < 2; ++n) {                              \
      b1[2 * n] = *(const s8v*)(bB[SL][0] + 4096 + n * 2048);                    \
      b1[2 * n + 1] = *(const s8v*)(bB[SL][1] + 4096 + n * 2048);                \
    }                                                                            \
    gload16(Agt + (size_t)128 * KK, dA[SN] + 16384);                             \
    gload16(Agt + (size_t)192 * KK, dA[SN] + 24576);                             \
    __builtin_amdgcn_s_setprio(1);                                               \
    _Pragma("unroll") for (int m = 0; m < 4; ++m)                                \
        _Pragma("unroll") for (int n = 0; n < 2; ++n) {                          \
      acc[m][2 + n] = __builtin_amdgcn_mfma_f32_16x16x32_bf16(                   \
          a[2 * m], b1[2 * n], acc[m][2 + n], 0, 0, 0);                          \
      acc[m][2 + n] = __builtin_amdgcn_mfma_f32_16x16x32_bf16(                   \
          a[2 * m + 1], b1[2 * n + 1], acc[m][2 + n], 0, 0, 0);                  \
    }                                                                            \
    __builtin_amdgcn_s_setprio(0);                                               \
    /* ---- ph2: quadrant (mh1,nh1), overwrite a ---- */                         \
    _Pragma("unroll") for (int m = 0; m < 4; ++m) {                              \
      a[2 * m] = *(const s8v*)(bA[SL][0] + 8192 + m * 2048);                     \
      a[2 * m + 1] = *(const s8v*)(bA[SL][1] + 8192 + m * 2048);                 \
    }                                                                            \
    gload16(Bgt, dB[SN]);                                                        \
    gload16(Bgt + (size_t)64 * KK, dB[SN] + 8192);                               \
    __builtin_amdgcn_s_setprio(1);                                               \
    _Pragma("unroll") for (int m = 0; m < 4; ++m)                                \
        _Pragma("unroll") for (int n = 0; n < 2; ++n) {                          \
      acc[4 + m][2 + n] = __builtin_amdgcn_mfma_f32_16x16x32_bf16(               \
          a[2 * m], b1[2 * n], acc[4 + m][2 + n], 0, 0, 0);                      \
      acc[4 + m][2 + n] = __builtin_amdgcn_mfma_f32_16x16x32_bf16(               \
          a[2 * m + 1], b1[2 * n + 1], acc[4 + m][2 + n], 0, 0, 0);              \
    }                                                                            \
    __builtin_amdgcn_s_setprio(0);                                               \
    /* ---- ph3: quadrant (mh1,nh0), b0 still live ---- */                       \
    gload16(Bgt + (size_t)128 * KK, dB[SN] + 16384);                             \
    gload16(Bgt + (size_t)192 * KK, dB[SN] + 24576);                             \
    __builtin_amdgcn_s_setprio(1);                                               \
    _Pragma("unroll") for (int m = 0; m < 4; ++m)                                \
        _Pragma("unroll") for (int n = 0; n < 2; ++n) {                          \
      acc[4 + m][n] = __builtin_amdgcn_mfma_f32_16x16x32_bf16(                   \
          a[2 * m], b0[2 * n], acc[4 + m][n], 0, 0, 0);                          \
      acc[4 + m][n] = __builtin_amdgcn_mfma_f32_16x16x32_bf16(                   \
          a[2 * m + 1], b0[2 * n + 1], acc[4 + m][n], 0, 0, 0);                  \
    }                                                                            \
    __builtin_amdgcn_s_setprio(0);                                               \
    asm volatile("s_waitcnt vmcnt(0)" ::: "memory");                             \
    __builtin_amdgcn_s_barrier();                                                \
    __builtin_amdgcn_sched_barrier(0);                                           \
  }

  for (int T = 0; T < NT; T += 2) {
    KV_ITER(T, 0, 1);
    KV_ITER((T + 1), 1, 0);
  }
#undef KV_ITER

  // ---- epilogue ----
  const int kq4 = kq * 4;
  if (EPI == 0) {
    const bool isK = (col0 < 1024);
    if (isK) {
#pragma unroll
      for (int ai = 0; ai < 8; ++ai) {
        int cols[4];
        float bb[4], gg[4];
#pragma unroll
        for (int n = 0; n < 4; ++n) {
          cols[n] = (int)col0 + wn * 64 + n * 16 + fr;
          bb[n] = biasK[cols[n]];
          gg[n] = gcol[cols[n]];
        }
#pragma unroll
        for (int r = 0; r < 4; ++r) {
          const size_t grow = row0 + wm * 128 + ai * 16 + kq4 + r;
          float v[4];
#pragma unroll
          for (int n = 0; n < 4; ++n) v[n] = acc[ai][n][r] + bb[n];
          float s = v[0] * v[0] + v[1] * v[1] + v[2] * v[2] + v[3] * v[3];
          s += __shfl_xor(s, 1);
          s += __shfl_xor(s, 2);
          s += __shfl_xor(s, 4);
          s += __shfl_xor(s, 8);
          if (fr == 0) atomicAdd(&rowssq[grow], s);
#pragma unroll
          for (int n = 0; n < 4; ++n)
            CK[grow * 1024 + cols[n]] = f2bf(v[n] * gg[n]);
        }
      }
    } else {
#pragma unroll
      for (int ai = 0; ai < 8; ++ai) {
        int cols[4];
        float bb[4];
#pragma unroll
        for (int n = 0; n < 4; ++n) {
          cols[n] = (int)col0 - 1024 + wn * 64 + n * 16 + fr;
          bb[n] = biasV[cols[n]];
        }
#pragma unroll
        for (int r = 0; r < 4; ++r) {
          const size_t grow = row0 + wm * 128 + ai * 16 + kq4 + r;
#pragma unroll
          for (int n = 0; n < 4; ++n)
            CV[grow * 1024 + cols[n]] = f2bf(acc[ai][n][r] + bb[n]);
        }
      }
    }
  } else {
#pragma unroll
    for (int ai = 0; ai < 8; ++ai) {
      int cols[4];
      float bb[4];
#pragma unroll
      for (int n = 0; n < 4; ++n) {
        cols[n] = (int)col0 + wn * 64 + n * 16 + fr;
        bb[n] = biasK[cols[n]];
      }
#pragma unroll
      for (int r = 0; r < 4; ++r) {
        const size_t grow = row0 + wm * 128 + ai * 16 + kq4 + r;
#pragma unroll
        for (int n = 0; n < 4; ++n) {
          const float x = acc[ai][n][r] + bb[n];
          CK[grow * (size_t)N + cols[n]] = f2bf(0.5f * x * (1.f + erff(x * 0.70710678118654752f)));
        }
      }
    }
  }
}

// ---------------- 128x128 MFMA GEMM (m97 structure), epilogues ---------------
// EPI 3: store f32 (acc+bias+extra[row,col])
// EPI 5: v=acc+bias; atomic rowssq += v^2; store bf16 v   (q-path)
// EPI 6: split-K partial: store f32 raw acc to Cv + z*M*N; K-range by blockIdx.z
template <int EPI>
__global__ __launch_bounds__(256) void gemm_bt(
    const u16* __restrict__ A, const u16* __restrict__ Bt,
    const float* __restrict__ bias, const float* __restrict__ gcol,
    void* __restrict__ Cv, const float* __restrict__ extra,
    float* __restrict__ rowssq, int M, int N, int K) {
  __shared__ u16 As[128 * 32];
  __shared__ u16 Bs[128 * 32];
  const int t = threadIdx.x;
  const int lane = t & 63;
  const int wave = t >> 6;
  const int wr = wave >> 1, wc = wave & 1;
  const size_t row0 = (size_t)blockIdx.y * 128;
  const size_t col0 = (size_t)blockIdx.x * 128;
  int Ksub = K, koff = 0;
  if (EPI == 6) { Ksub = K / gridDim.z; koff = blockIdx.z * Ksub; }

  f4v acc[4][4];
#pragma unroll
  for (int m = 0; m < 4; ++m)
#pragma unroll
    for (int n = 0; n < 4; ++n) acc[m][n] = (f4v){0.f, 0.f, 0.f, 0.f};

  const int sr = t >> 2;
  const int scw = (((t & 3) ^ ((t >> 3) & 3)) << 3);  // pre-swizzled global col
  const u16* Ag = A + (row0 + sr) * (size_t)K + koff + scw;
  const u16* Bg = Bt + (col0 + sr) * (size_t)K + koff + scw;
  u16* Al = &As[t * 8];  // linear dest
  u16* Bl = &Bs[t * 8];
  const int fr = lane & 15;
  const int kx = (((lane >> 4) ^ ((fr >> 1) & 3)) << 3);

  for (int k0 = 0; k0 < Ksub; k0 += 32) {
    gload16(Ag + k0, Al);
    gload16(Ag + k0 + (size_t)64 * K, Al + 64 * 32);
    gload16(Bg + k0, Bl);
    gload16(Bg + k0 + (size_t)64 * K, Bl + 64 * 32);
    __syncthreads();
    s8v a[4], b[4];
#pragma unroll
    for (int m = 0; m < 4; ++m)
      a[m] = *(const s8v*)&As[(wr * 64 + m * 16 + fr) * 32 + kx];
#pragma unroll
    for (int n = 0; n < 4; ++n)
      b[n] = *(const s8v*)&Bs[(wc * 64 + n * 16 + fr) * 32 + kx];
#pragma unroll
    for (int m = 0; m < 4; ++m)
#pragma unroll
      for (int n = 0; n < 4; ++n)
        acc[m][n] = __builtin_amdgcn_mfma_f32_16x16x32_bf16(a[m], b[n], acc[m][n], 0, 0, 0);
    __syncthreads();
  }

  float* Cp = (float*)Cv;
  if (EPI == 6) Cp += (size_t)blockIdx.z * M * (size_t)N;
  const int rg = (lane >> 4) * 4;
#pragma unroll
  for (int m = 0; m < 4; ++m) {
    int cols[4];
    float bvals[4];
#pragma unroll
    for (int n = 0; n < 4; ++n) {
      cols[n] = (int)col0 + wc * 64 + n * 16 + fr;
      bvals[n] = (EPI == 6) ? 0.f : bias[cols[n]];
    }
#pragma unroll
    for (int r = 0; r < 4; ++r) {
      const size_t grow = row0 + wr * 64 + m * 16 + rg + r;
      float v[4];
#pragma unroll
      for (int n = 0; n < 4; ++n) v[n] = acc[m][n][r] + bvals[n];
      if (EPI == 5) {
        float s = v[0] * v[0] + v[1] * v[1] + v[2] * v[2] + v[3] * v[3];
        s += __shfl_xor(s, 1);
        s += __shfl_xor(s, 2);
        s += __shfl_xor(s, 4);
        s += __shfl_xor(s, 8);
        if (fr == 0) atomicAdd(&rowssq[grow], s);
      }
#pragma unroll
      for (int n = 0; n < 4; ++n) {
        const size_t idx = grow * (size_t)N + cols[n];
        if (EPI == 3) {
          Cp[idx] = v[n] + extra[idx];
        } else if (EPI == 5) {
          ((u16*)Cv)[idx] = f2bf(v[n]);
        } else if (EPI == 6) {
          Cp[idx] = v[n];
        }
      }
    }
  }
}

// ---------------- attention with the faithful raw-reshape semantics ----------
// head h, key j in [0,32): kv position = 2h + j/16, d-slice = (j%16)*64 .. +64
// q applied here: q_eff[d] = qpre[d]*gq[d]*rsq_q*0.125 (rms of q folded)
__global__ __launch_bounds__(256) void attn_k(const u16* __restrict__ qf,
                                              const u16* __restrict__ kmat,
                                              const float* __restrict__ kssq,
                                              const u16* __restrict__ vmat,
                                              const float* __restrict__ gq,
                                              const float* __restrict__ qssq,
                                              u16* __restrict__ ao) {
  const int lb = blockIdx.x;
  const int t = threadIdx.x;
  const int wave = t >> 6, lane = t & 63;
  const int j = lane & 31, half = lane >> 5;
  const float rq = rsqrtf(qssq[lb] * (1.f / 1024.f) + 1e-6f) * 0.125f;
  __shared__ float po[64][17];
#pragma unroll
  for (int hi = 0; hi < 4; ++hi) {
    const int h = wave * 4 + hi;
    const int krow = lb * 32 + 2 * h + (j >> 4);
    const u16* kp = kmat + (size_t)krow * 1024 + (j & 15) * 64 + half * 32;
    const u16* qp = qf + (size_t)lb * 1024 + h * 64 + half * 32;
    const float* gqp = gq + h * 64 + half * 32;
    float s = 0.f;
#pragma unroll
    for (int cc = 0; cc < 4; ++cc) {
      s8v qv = *(const s8v*)(qp + cc * 8);
      s8v kv = *(const s8v*)(kp + cc * 8);
#pragma unroll
      for (int e = 0; e < 8; ++e)
        s += bf2f((u16)qv[e]) * gqp[cc * 8 + e] * bf2f((u16)kv[e]);
    }
    s += __shfl_xor(s, 32);
    s *= rsqrtf(kssq[krow] * (1.f / 1024.f) + 1e-6f) * rq;
    float mx = s;
#pragma unroll
    for (int m = 16; m >= 1; m >>= 1) mx = fmaxf(mx, __shfl_xor(mx, m));
    const float pe = __expf(s - mx);
    float sum = pe;
#pragma unroll
    for (int m = 16; m >= 1; m >>= 1) sum += __shfl_xor(sum, m);
    const float pr = pe / sum;
    float o = 0.f;
#pragma unroll
    for (int jj = 0; jj < 32; ++jj) {
      const int vrow = lb * 32 + 2 * h + (jj >> 4);
      const float vv = bf2f(vmat[(size_t)vrow * 1024 + (jj & 15) * 64 + lane]);
      o += __shfl(pr, jj) * vv;
    }
    po[lane][h] = o;  // hd = lane
  }
  __syncthreads();
  const int c = t * 4;
  u16x4 o4;
#pragma unroll
  for (int i = 0; i < 4; ++i) o4[i] = f2bf(po[(c + i) >> 4][(c + i) & 15]);
  *(u16x4*)(ao + (size_t)lb * 1024 + c) = o4;
}

// ------------- W2 split-K combine: out = p0 + p1 + b2[col] + resid -----------
__global__ __launch_bounds__(256) void combine_k(const float* __restrict__ p0,
                                                 const float* __restrict__ p1,
                                                 const float* __restrict__ b2,
                                                 const float* __restrict__ resid,
                                                 float* __restrict__ out) {
  const int i = blockIdx.x * 256 + threadIdx.x;  // float4 index
  float4 a = ((const float4*)p0)[i];
  float4 b = ((const float4*)p1)[i];
  float4 r = ((const float4*)resid)[i];
  float4 bb = ((const float4*)b2)[i & 255];
  float4 o;
  o.x = a.x + b.x + r.x + bb.x;
  o.y = a.y + b.y + r.y + bb.y;
  o.z = a.z + b.z + r.z + bb.z;
  o.w = a.w + b.w + r.w + bb.w;
  ((float4*)out)[i] = o;
}

// -----------------------------------------------------------------------------
extern "C" void kernel_launch(void* const* d_in, const int* in_sizes, int n_in,
                              void* d_out, int out_size, void* d_ws, size_t ws_size,
                              hipStream_t stream) {
  const float* query  = (const float*)d_in[0];
  const float* pf     = (const float*)d_in[1];
  const float* lnq_g  = (const float*)d_in[2];
  const float* lnq_b  = (const float*)d_in[3];
  const float* lnkv_g = (const float*)d_in[4];
  const float* lnkv_b = (const float*)d_in[5];
  const float* Wq     = (const float*)d_in[6];
  const float* bq     = (const float*)d_in[7];
  const float* Wk     = (const float*)d_in[8];
  const float* bk     = (const float*)d_in[9];
  const float* Wv     = (const float*)d_in[10];
  const float* bv     = (const float*)d_in[11];
  const float* rmsq_g = (const float*)d_in[12];
  const float* rmsk_g = (const float*)d_in[13];
  const float* Wo     = (const float*)d_in[14];
  const float* bo     = (const float*)d_in[15];
  const float* mlpn_g = (const float*)d_in[16];
  const float* mlpn_b = (const float*)d_in[17];
  const float* W1     = (const float*)d_in[18];
  const float* b1     = (const float*)d_in[19];
  const float* W2     = (const float*)d_in[20];
  const float* b2     = (const float*)d_in[21];
  float* out = (float*)d_out;

  char* p = (char*)d_ws;
  auto alloc = [&](size_t n) {
    char* r = p;
    p += (n + 255) & ~(size_t)255;
    return r;
  };

  u16* Wqt = (u16*)alloc((size_t)1024 * 1024 * 2);
  u16* KVt = (u16*)alloc((size_t)2048 * 1024 * 2);  // [Wk^T ; Wv^T]
  u16* Wot = (u16*)alloc((size_t)1024 * 1024 * 2);
  u16* W1t = (u16*)alloc((size_t)1024 * 4096 * 2);
  u16* W2t = (u16*)alloc((size_t)4096 * 1024 * 2);
  u16* qln = (u16*)alloc((size_t)4096 * 1024 * 2);
  u16* qpre = (u16*)alloc((size_t)4096 * 1024 * 2);
  float* qssq = (float*)alloc((size_t)4096 * 4);
  u16* attn_o = (u16*)alloc((size_t)4096 * 1024 * 2);
  float* outbuf = (float*)alloc((size_t)4096 * 1024 * 4);
  u16* hbuf = (u16*)alloc((size_t)4096 * 1024 * 2);
  u16* mid = (u16*)alloc((size_t)4096 * 4096 * 2);
  float* w2p = (float*)alloc((size_t)2 * 4096 * 1024 * 4);  // split-K partials

  // chunked KV pipeline buffers (NC chunks; chunk data stays L3-resident)
  const size_t used = (size_t)(p - (char*)d_ws);
  int NC = 4;
  while (NC < 64) {
    size_t rows_try = (size_t)131072 / NC;
    if (used + 3 * (rows_try * 2048 + 256) + rows_try * 4 + 256 <= ws_size) break;
    NC *= 2;
  }
  const size_t rows = (size_t)131072 / NC;
  u16* kvln = (u16*)alloc(rows * 2048);
  u16* kmat = (u16*)alloc(rows * 2048);
  u16* vmat = (u16*)alloc(rows * 2048);
  float* kssq = (float*)alloc(rows * 4);

  // weight transpose+convert: W[K][N] f32 -> Wt[N][K] bf16
  transpose_w<<<dim3(32, 32), 256, 0, stream>>>(Wq, Wqt, 1024, 1024);
  transpose_w<<<dim3(32, 32), 256, 0, stream>>>(Wk, KVt, 1024, 1024);
  transpose_w<<<dim3(32, 32), 256, 0, stream>>>(Wv, KVt + (size_t)1024 * 1024, 1024, 1024);
  transpose_w<<<dim3(32, 32), 256, 0, stream>>>(Wo, Wot, 1024, 1024);
  transpose_w<<<dim3(128, 32), 256, 0, stream>>>(W1, W1t, 1024, 4096);
  transpose_w<<<dim3(32, 128), 256, 0, stream>>>(W2, W2t, 4096, 1024);

  // q path: LN -> GEMM(Wq)+bq (epilogue: bf16 qpre + qssq atomics)
  ln_rows<<<4096, 256, 0, stream>>>(query, lnq_g, lnq_b, qln, qssq);
  gemm_bt<5><<<dim3(8, 32), 256, 0, stream>>>(qln, Wqt, bq, nullptr, qpre, nullptr,
                                              qssq, 4096, 1024, 1024);

  // kv path: chunked ln -> fused K+V gemm256 -> attn (chunk stays in L3)
  const int bpc = 4096 / NC;
  const int RB = (int)(rows / 256);
  for (int c = 0; c < NC; ++c) {
    ln_rows<<<(unsigned)rows, 256, 0, stream>>>(pf + (size_t)c * rows * 1024, lnkv_g,
                                                lnkv_b, kvln, kssq);
    gemm256<0, 1024><<<RB * 8, 512, 0, stream>>>(kvln, KVt, bk, bv, rmsk_g, kmat, vmat,
                                                 kssq, (int)rows, 2048, RB, 8);
    attn_k<<<bpc, 256, 0, stream>>>(qpre + (size_t)c * bpc * 1024, kmat, kssq, vmat,
                                    rmsq_g, qssq + (size_t)c * bpc,
                                    attn_o + (size_t)c * bpc * 1024);
  }

  // out = attn_o @ Wo + bo + query  (f32)
  gemm_bt<3><<<dim3(8, 32), 256, 0, stream>>>(attn_o, Wot, bo, nullptr, outbuf, query,
                                              nullptr, 4096, 1024, 1024);
  // h = LN(out)
  ln_rows<<<4096, 256, 0, stream>>>(outbuf, mlpn_g, mlpn_b, hbuf, nullptr);
  // mid = gelu(h @ W1 + b1)  -- 256^2 kernel, grid 16x16
  gemm256<1, 1024><<<16 * 16, 512, 0, stream>>>(hbuf, W1t, b1, nullptr, nullptr, mid,
                                                nullptr, nullptr, 4096, 4096, 16, 16);
  // final = mid @ W2 (split-K=2 partials) + b2 + out
  gemm_bt<6><<<dim3(8, 32, 2), 256, 0, stream>>>(mid, W2t, nullptr, nullptr, w2p,
                                                 nullptr, nullptr, 4096, 1024, 4096);
  combine_k<<<4096, 256, 0, stream>>>(w2p, w2p + (size_t)4096 * 1024, b2, outbuf, out);
}